// Round 4
// baseline (404.376 us; speedup 1.0000x reference)
//
#include <hip/hip_runtime.h>

#define IN_C 512
#define OUT_C 1024
#define NC2 2048
#define NEG_SLOPE 0.2f

typedef short frag8 __attribute__((ext_vector_type(8)));
typedef float f32x4 __attribute__((ext_vector_type(4)));

#define GLOAD_LDS16(g, l) __builtin_amdgcn_global_load_lds(\
    (const __attribute__((address_space(1))) void*)(g), \
    (__attribute__((address_space(3))) void*)(l), 16, 0, 0)

__device__ __forceinline__ unsigned short f2b(float f){
  unsigned u = __float_as_uint(f);
  unsigned r = (u + 0x7fffu + ((u >> 16) & 1u)) >> 16;
  return (unsigned short)r;
}
__device__ __forceinline__ unsigned encf(float f){
  unsigned u = __float_as_uint(f);
  return (u & 0x80000000u) ? ~u : (u | 0x80000000u);
}
__device__ __forceinline__ float decf(unsigned u){
  unsigned v = (u & 0x80000000u) ? (u & 0x7fffffffu) : ~u;
  return __uint_as_float(v);
}
__device__ __forceinline__ float leaky(float v){ return v >= 0.f ? v : NEG_SLOPE * v; }

// ---------------- conversion / transpose ----------------

__global__ void cvt_x_kernel(const float* __restrict__ x, unsigned short* __restrict__ xb, int total4){
  int i = blockIdx.x * 256 + threadIdx.x;
  if (i >= total4) return;
  float4 v = ((const float4*)x)[i];
  ushort4 o;
  o.x = f2b(v.x); o.y = f2b(v.y); o.z = f2b(v.z); o.w = f2b(v.w);
  ((ushort4*)xb)[i] = o;
}

__global__ void transpose_cvt_kernel(const float* __restrict__ in, unsigned short* __restrict__ out,
                                     int R, int C, int rowOff){
  __shared__ float tile[32][33];
  int c0 = blockIdx.x * 32, r0 = blockIdx.y * 32;
  for (int i = threadIdx.y; i < 32; i += 8)
    tile[i][threadIdx.x] = in[(size_t)(r0 + i) * C + c0 + threadIdx.x];
  __syncthreads();
  for (int i = threadIdx.y; i < 32; i += 8)
    out[(size_t)(c0 + i + rowOff) * R + r0 + threadIdx.x] = f2b(tile[threadIdx.x][i]);
}

// ---------------- attention-logit precompute ----------------

__global__ void uv_kernel(const float* __restrict__ W1, const float* __restrict__ W2,
                          const float* __restrict__ a_src1, const float* __restrict__ a_dst1,
                          const float* __restrict__ a_src2, const float* __restrict__ a_dst2,
                          float* __restrict__ uv){
  int g = blockIdx.x * 4 + (threadIdx.x >> 6);
  int lane = threadIdx.x & 63;
  int which = g >> 9;
  int i = g & 511;
  const float* W = (which < 2) ? W1 : W2;
  const float* a = (which == 0) ? a_src1 : (which == 1) ? a_dst1 : (which == 2) ? a_src2 : a_dst2;
  const float* row = W + (size_t)i * OUT_C;
  float s = 0.f;
  for (int j = lane; j < OUT_C; j += 64) s += row[j] * a[j];
  for (int off = 32; off; off >>= 1) s += __shfl_down(s, off);
  if (lane == 0) uv[which * IN_C + i] = s;
}

// alpha + fused selfinit
__global__ void alpha_kernel(const float* __restrict__ x, const float* __restrict__ uv,
                             float* __restrict__ as1, float* __restrict__ ad1,
                             float* __restrict__ as2, float* __restrict__ ad2,
                             float* __restrict__ self1, float* __restrict__ self2,
                             unsigned* __restrict__ m1e, unsigned* __restrict__ m2e){
  int n = blockIdx.x;
  int w = threadIdx.x >> 6, lane = threadIdx.x & 63;
  __shared__ float sh[4];
  const float* row = x + (size_t)n * IN_C;
  const float* u = uv + w * IN_C;
  float s = 0.f;
  for (int j = lane; j < IN_C; j += 64) s += row[j] * u[j];
  for (int off = 32; off; off >>= 1) s += __shfl_down(s, off);
  if (lane == 0){
    sh[w] = s;
    if (w == 0) as1[n] = s;
    else if (w == 1) ad1[n] = s;
    else if (w == 2) as2[n] = s;
    else ad2[n] = s;
  }
  __syncthreads();
  if (threadIdx.x == 0){
    float e1 = leaky(sh[0] + sh[1]);
    float e2 = leaky(sh[2] + sh[3]);
    self1[n] = e1; self2[n] = e2;
    m1e[n] = encf(e1); m2e[n] = encf(e2);
  }
}

// ---------------- CSR build ----------------

__global__ void zero_kernel(int* counts, int* cursor, float* colsum, float* wv, int N){
  int i = blockIdx.x * 256 + threadIdx.x;
  if (i < N){ counts[i] = 0; cursor[i] = 0; }
  if (i < OUT_C){ colsum[i] = 0.f; wv[i] = 0.f; }
}

__global__ void hist_kernel(const int* __restrict__ dst, int* counts, int E){
  int e = blockIdx.x * 256 + threadIdx.x;
  if (e < E) atomicAdd(&counts[dst[e]], 1);
}

__global__ void scan_kernel(const int* __restrict__ counts, int* __restrict__ offs, int n){
  __shared__ int wsum[4];
  int tid = threadIdx.x;
  int wave = tid >> 6, lane = tid & 63;
  int carry = 0;
  for (int base = 0; base < n; base += 256){
    int i = base + tid;
    int v = (i < n) ? counts[i] : 0;
    int sc = v;
    for (int o = 1; o < 64; o <<= 1){
      int t = __shfl_up(sc, o);
      if (lane >= o) sc += t;
    }
    if (lane == 63) wsum[wave] = sc;
    __syncthreads();
    int wp = 0, tot = 0;
#pragma unroll
    for (int k = 0; k < 4; k++){
      int ws = wsum[k];
      if (k < wave) wp += ws;
      tot += ws;
    }
    if (i < n) offs[i] = carry + wp + sc - v;
    carry += tot;
    __syncthreads();
  }
}

__global__ void scatter_kernel(const int* __restrict__ dst, const int* __restrict__ offs,
                               int* cursor, int* __restrict__ pose, int E){
  int e = blockIdx.x * 256 + threadIdx.x;
  if (e < E){
    int d = dst[e];
    int p = atomicAdd(&cursor[d], 1);
    pose[e] = offs[d] + p;
  }
}

// ---------------- edge softmax ----------------

__global__ void edgemax_kernel(const int* __restrict__ src, const int* __restrict__ dst,
                               const float* __restrict__ as1, const float* __restrict__ ad1,
                               const float* __restrict__ as2, const float* __restrict__ ad2,
                               unsigned* m1e, unsigned* m2e, int E){
  int e = blockIdx.x * 256 + threadIdx.x;
  if (e >= E) return;
  int s = src[e], d = dst[e];
  atomicMax(&m1e[d], encf(leaky(as1[s] + ad1[d])));
  atomicMax(&m2e[d], encf(leaky(as2[s] + ad2[d])));
}

__global__ void denominit_kernel(const unsigned* __restrict__ m1e, const unsigned* __restrict__ m2e,
                                 const float* __restrict__ self1, const float* __restrict__ self2,
                                 float* __restrict__ m1, float* __restrict__ m2,
                                 float* __restrict__ den1, float* __restrict__ den2, int N){
  int i = blockIdx.x * 256 + threadIdx.x;
  if (i >= N) return;
  float a = decf(m1e[i]), b = decf(m2e[i]);
  m1[i] = a; m2[i] = b;
  den1[i] = expf(self1[i] - a);
  den2[i] = expf(self2[i] - b);
}

__global__ void edgeexp_kernel(const int* __restrict__ src, const int* __restrict__ dst,
                               const float* __restrict__ as1, const float* __restrict__ ad1,
                               const float* __restrict__ as2, const float* __restrict__ ad2,
                               const float* __restrict__ m1, const float* __restrict__ m2,
                               const int* __restrict__ pose,
                               int* __restrict__ nsrc, float* __restrict__ nw1, float* __restrict__ nw2,
                               float* den1, float* den2, int E){
  int e = blockIdx.x * 256 + threadIdx.x;
  if (e >= E) return;
  int s = src[e], d = dst[e];
  float x1 = expf(leaky(as1[s] + ad1[d]) - m1[d]);
  float x2 = expf(leaky(as2[s] + ad2[d]) - m2[d]);
  int p = pose[e];
  nsrc[p] = s; nw1[p] = x1; nw2[p] = x2;
  atomicAdd(&den1[d], x1);
  atomicAdd(&den2[d], x2);
}

// ---------------- aggregate-first: xa_w[d][:] = sum_e w_e * x[src_e][:] ----------------
// grid (4, N/16): slice = blockIdx.x (128 x-cols, 2.5 MB slice -> L2-resident, XCD-pinned mod 4).
// block 256 = 16 groups x 16 lanes; group -> dst node; lane -> 8 cols (16B load),
// dual accumulation (w1 and w2) per load.

#define AGG_FMA8(ACC, W, U) \
  ACC[0] += (W) * __uint_as_float(((unsigned)(U).x) << 16); \
  ACC[1] += (W) * __uint_as_float(((unsigned)(U).x) & 0xffff0000u); \
  ACC[2] += (W) * __uint_as_float(((unsigned)(U).y) << 16); \
  ACC[3] += (W) * __uint_as_float(((unsigned)(U).y) & 0xffff0000u); \
  ACC[4] += (W) * __uint_as_float(((unsigned)(U).z) << 16); \
  ACC[5] += (W) * __uint_as_float(((unsigned)(U).z) & 0xffff0000u); \
  ACC[6] += (W) * __uint_as_float(((unsigned)(U).w) << 16); \
  ACC[7] += (W) * __uint_as_float(((unsigned)(U).w) & 0xffff0000u);

__global__ __launch_bounds__(256) void aggx_kernel(
    const int* __restrict__ counts, const int* __restrict__ offs,
    const int* __restrict__ nsrc, const float* __restrict__ nw1, const float* __restrict__ nw2,
    const float* __restrict__ den1, const float* __restrict__ den2,
    const float* __restrict__ self1, const float* __restrict__ self2,
    const float* __restrict__ m1, const float* __restrict__ m2,
    const unsigned short* __restrict__ xb,
    unsigned short* __restrict__ xa1b, unsigned short* __restrict__ xa2b, int N){
  int tid = threadIdx.x;
  int g = tid >> 4, hl = tid & 15;
  int grpbase = tid & 48;               // 4 groups per 64-lane wave
  int d = blockIdx.y * 16 + g;
  if (d >= N) return;
  int colbase = blockIdx.x * 128 + hl * 8;
  float inv1 = 1.f / den1[d], inv2 = 1.f / den2[d];
  int deg = counts[d], off = offs[d];
  float acc1[8] = {0,0,0,0,0,0,0,0}, acc2[8] = {0,0,0,0,0,0,0,0};
  const unsigned short* Xb = xb + colbase;
  for (int base = 0; base < deg; base += 16){
    int i = base + hl;
    int s = 0; float w1 = 0.f, w2 = 0.f;
    if (i < deg){
      int p = off + i;
      s = nsrc[p];
      w1 = nw1[p] * inv1;
      w2 = nw2[p] * inv2;
    }
    int cnt = min(16, deg - base);
#pragma unroll 4
    for (int j = 0; j < cnt; j++){
      int sj = __shfl(s, grpbase + j);
      float w1j = __shfl(w1, grpbase + j);
      float w2j = __shfl(w2, grpbase + j);
      int4 u = *(const int4*)(Xb + (size_t)sj * IN_C);
      AGG_FMA8(acc1, w1j, u)
      AGG_FMA8(acc2, w2j, u)
    }
  }
  // self loop
  {
    float ws1 = expf(self1[d] - m1[d]) * inv1;
    float ws2 = expf(self2[d] - m2[d]) * inv2;
    int4 u = *(const int4*)(Xb + (size_t)d * IN_C);
    AGG_FMA8(acc1, ws1, u)
    AGG_FMA8(acc2, ws2, u)
  }
  size_t outb = (size_t)d * IN_C + colbase;
  int4 o1, o2;
  o1.x = (int)((unsigned)f2b(acc1[0]) | ((unsigned)f2b(acc1[1]) << 16));
  o1.y = (int)((unsigned)f2b(acc1[2]) | ((unsigned)f2b(acc1[3]) << 16));
  o1.z = (int)((unsigned)f2b(acc1[4]) | ((unsigned)f2b(acc1[5]) << 16));
  o1.w = (int)((unsigned)f2b(acc1[6]) | ((unsigned)f2b(acc1[7]) << 16));
  o2.x = (int)((unsigned)f2b(acc2[0]) | ((unsigned)f2b(acc2[1]) << 16));
  o2.y = (int)((unsigned)f2b(acc2[2]) | ((unsigned)f2b(acc2[3]) << 16));
  o2.z = (int)((unsigned)f2b(acc2[4]) | ((unsigned)f2b(acc2[5]) << 16));
  o2.w = (int)((unsigned)f2b(acc2[6]) | ((unsigned)f2b(acc2[7]) << 16));
  *(int4*)(xa1b + outb) = o1;
  *(int4*)(xa2b + outb) = o2;
}

// ---------------- GEMM-H: h_w = prelu(xa_w @ W_w + b_w); pass2 also hsum=bf16(h1+h2) -------

__global__ __launch_bounds__(256) void gemmh_kernel(const unsigned short* __restrict__ A,
                                                    const unsigned short* __restrict__ BT,
                                                    const float* __restrict__ bias,
                                                    const float* __restrict__ prelu_a,
                                                    float* __restrict__ hout,
                                                    const float* __restrict__ h1in,
                                                    unsigned short* __restrict__ hsum,
                                                    int M, int pass2){
  __shared__ unsigned short Al[128 * 32];
  __shared__ unsigned short Bl[128 * 32];
  const int t = threadIdx.x;
  const int lane = t & 63, wid = t >> 6;
  const int wi = wid & 1, wj = wid >> 1;
  const int l16 = lane & 15, q = lane >> 4;
  const int bm = blockIdx.y * 128, bn = blockIdx.x * 128;
  const int lrow = lane >> 2;
  const int lch = (lane & 3) * 8;
  f32x4 acc[4][4] = {};
  for (int k0 = 0; k0 < IN_C; k0 += 32){
    int r0 = wid * 32 + lrow;
    int r1 = r0 + 16;
    int ga0 = min(bm + r0, M - 1);
    int ga1 = min(bm + r1, M - 1);
    GLOAD_LDS16(A + (size_t)ga0 * IN_C + k0 + lch, &Al[(wid * 32) * 32]);
    GLOAD_LDS16(A + (size_t)ga1 * IN_C + k0 + lch, &Al[(wid * 32 + 16) * 32]);
    GLOAD_LDS16(BT + (size_t)(bn + r0) * IN_C + k0 + lch, &Bl[(wid * 32) * 32]);
    GLOAD_LDS16(BT + (size_t)(bn + r1) * IN_C + k0 + lch, &Bl[(wid * 32 + 16) * 32]);
    __syncthreads();
    frag8 af[4], bf[4];
#pragma unroll
    for (int mi = 0; mi < 4; mi++) af[mi] = *(const frag8*)&Al[(wi*64 + mi*16 + l16) * 32 + q*8];
#pragma unroll
    for (int nj = 0; nj < 4; nj++) bf[nj] = *(const frag8*)&Bl[(wj*64 + nj*16 + l16) * 32 + q*8];
#pragma unroll
    for (int mi = 0; mi < 4; mi++)
#pragma unroll
      for (int nj = 0; nj < 4; nj++)
        acc[mi][nj] = __builtin_amdgcn_mfma_f32_16x16x32_bf16(af[mi], bf[nj], acc[mi][nj], 0, 0, 0);
    __syncthreads();
  }
  float pa = prelu_a[0];
#pragma unroll
  for (int mi = 0; mi < 4; mi++){
#pragma unroll
    for (int r = 0; r < 4; r++){
      int row = bm + wi*64 + mi*16 + q*4 + r;
      if (row >= M) continue;
#pragma unroll
      for (int nj = 0; nj < 4; nj++){
        int col = bn + wj*64 + nj*16 + l16;
        float v = acc[mi][nj][r] + bias[col];
        v = v >= 0.f ? v : pa * v;
        size_t idx = (size_t)row * OUT_C + col;
        hout[idx] = v;
        if (pass2) hsum[idx] = f2b(v + h1in[idx]);
      }
    }
  }
}

// ---------------- GEMM2: colsum += sum_rows tanh(hsum @ Wp1 + bp1) ----------------

__global__ __launch_bounds__(256) void gemm2_kernel(const unsigned short* __restrict__ A,
                                                    const unsigned short* __restrict__ BT,
                                                    const float* __restrict__ bp1,
                                                    float* __restrict__ colsum, int M){
  __shared__ unsigned short Al[128 * 32];
  __shared__ unsigned short Bl[128 * 32];
  __shared__ float cs[128];
  const int t = threadIdx.x;
  const int lane = t & 63, wid = t >> 6;
  const int wi = wid & 1, wj = wid >> 1;
  const int l16 = lane & 15, q = lane >> 4;
  const int bm = blockIdx.y * 128, bn = blockIdx.x * 128;
  const int lrow = lane >> 2;
  const int lch = (lane & 3) * 8;
  if (t < 128) cs[t] = 0.f;
  f32x4 acc[4][4] = {};
  for (int k0 = 0; k0 < OUT_C; k0 += 32){
    int r0 = wid * 32 + lrow;
    int r1 = r0 + 16;
    int ga0 = min(bm + r0, M - 1);
    int ga1 = min(bm + r1, M - 1);
    GLOAD_LDS16(A + (size_t)ga0 * OUT_C + k0 + lch, &Al[(wid * 32) * 32]);
    GLOAD_LDS16(A + (size_t)ga1 * OUT_C + k0 + lch, &Al[(wid * 32 + 16) * 32]);
    GLOAD_LDS16(BT + (size_t)(bn + r0) * OUT_C + k0 + lch, &Bl[(wid * 32) * 32]);
    GLOAD_LDS16(BT + (size_t)(bn + r1) * OUT_C + k0 + lch, &Bl[(wid * 32 + 16) * 32]);
    __syncthreads();
    frag8 af[4], bf[4];
#pragma unroll
    for (int mi = 0; mi < 4; mi++) af[mi] = *(const frag8*)&Al[(wi*64 + mi*16 + l16) * 32 + q*8];
#pragma unroll
    for (int nj = 0; nj < 4; nj++) bf[nj] = *(const frag8*)&Bl[(wj*64 + nj*16 + l16) * 32 + q*8];
#pragma unroll
    for (int mi = 0; mi < 4; mi++)
#pragma unroll
      for (int nj = 0; nj < 4; nj++)
        acc[mi][nj] = __builtin_amdgcn_mfma_f32_16x16x32_bf16(af[mi], bf[nj], acc[mi][nj], 0, 0, 0);
    __syncthreads();
  }
#pragma unroll
  for (int nj = 0; nj < 4; nj++){
    int col = bn + wj*64 + nj*16 + l16;
    float bias = bp1[col];
    float p = 0.f;
#pragma unroll
    for (int mi = 0; mi < 4; mi++){
#pragma unroll
      for (int r = 0; r < 4; r++){
        int row = bm + wi*64 + mi*16 + q*4 + r;
        float tv = tanhf(acc[mi][nj][r] + bias);
        if (row < M) p += tv;
      }
    }
    p += __shfl_xor(p, 16);
    p += __shfl_xor(p, 32);
    if (q == 0) atomicAdd(&cs[wj*64 + nj*16 + l16], p);
  }
  __syncthreads();
  if (t < 128) atomicAdd(&colsum[bn + t], cs[t]);
}

// ---------------- semantic attention tail ----------------

__global__ void wproj_kernel(const float* __restrict__ colsum, const float* __restrict__ Wp2,
                             float* __restrict__ wv){
  int o = blockIdx.x * 256 + threadIdx.x;
  int c0 = blockIdx.y * 128;
  float acc = 0.f;
  for (int c = c0; c < c0 + 128; c++) acc += colsum[c] * Wp2[(size_t)c * OUT_C + o];
  atomicAdd(&wv[o], acc);
}

__global__ __launch_bounds__(1024) void softmax_kernel(const float* __restrict__ wv,
                                                       float* __restrict__ att, float invN){
  int o = threadIdx.x;
  __shared__ float red[1024];
  float w = wv[o] * invN;
  red[o] = w; __syncthreads();
  for (int s = 512; s > 0; s >>= 1){ if (o < s) red[o] = fmaxf(red[o], red[o + s]); __syncthreads(); }
  float m = red[0]; __syncthreads();
  float e = expf(w - m);
  red[o] = e; __syncthreads();
  for (int s = 512; s > 0; s >>= 1){ if (o < s) red[o] += red[o + s]; __syncthreads(); }
  att[o] = e / red[0];
}

__global__ void combine_kernel(const float* __restrict__ att, const float* h1,
                               const float* __restrict__ h2, float* out, int total4){
  int i = blockIdx.x * 256 + threadIdx.x;
  if (i >= total4) return;
  float4 a = ((const float4*)att)[i & 255];
  float4 v1 = ((const float4*)h1)[i];
  float4 v2 = ((const float4*)h2)[i];
  float4 o;
  o.x = a.x * v1.x + (1.f - a.x) * v2.x;
  o.y = a.y * v1.y + (1.f - a.y) * v2.y;
  o.z = a.z * v1.z + (1.f - a.z) * v2.z;
  o.w = a.w * v1.w + (1.f - a.w) * v2.w;
  ((float4*)out)[i] = o;
}

// ---------------- launch ----------------

extern "C" void kernel_launch(void* const* d_in, const int* in_sizes, int n_in,
                              void* d_out, int out_size, void* d_ws, size_t ws_size,
                              hipStream_t stream){
  const float* x      = (const float*)d_in[0];
  const int*   edge   = (const int*)d_in[1];
  const float* W1     = (const float*)d_in[2];
  const float* a_src1 = (const float*)d_in[3];
  const float* a_dst1 = (const float*)d_in[4];
  const float* b1     = (const float*)d_in[5];
  const float* W2     = (const float*)d_in[6];
  const float* a_src2 = (const float*)d_in[7];
  const float* a_dst2 = (const float*)d_in[8];
  const float* b2     = (const float*)d_in[9];
  const float* prelu_a= (const float*)d_in[10];
  const float* Wp1    = (const float*)d_in[11];
  const float* bp1    = (const float*)d_in[12];
  const float* Wp2    = (const float*)d_in[13];
  const int N = in_sizes[0] / IN_C;
  const int E = in_sizes[1] / 2;
  const int* srcArr = edge;
  const int* dstArr = edge + E;

  char* ws = (char*)d_ws;
  size_t o = 0;
  auto alloc = [&](size_t b) -> char* {
    char* p = ws + o;
    o = (o + b + 255) & ~(size_t)255;
    return p;
  };
  unsigned short* xb    = (unsigned short*)alloc((size_t)N * IN_C * 2);
  unsigned short* WT    = (unsigned short*)alloc((size_t)NC2 * IN_C * 2);   // [2048][512]: W1^T | W2^T
  unsigned short* Wp1T  = (unsigned short*)alloc((size_t)OUT_C * OUT_C * 2);
  unsigned short* xa1b  = (unsigned short*)alloc((size_t)N * IN_C * 2);
  unsigned short* xa2b  = (unsigned short*)alloc((size_t)N * IN_C * 2);
  float*          hout2 = (float*)alloc((size_t)N * OUT_C * 4);
  unsigned short* hsum  = (unsigned short*)alloc((size_t)N * OUT_C * 2);
  float*          uv    = (float*)alloc(4 * IN_C * 4);
  float*          as1   = (float*)alloc((size_t)4 * N * 4);
  float* ad1 = as1 + N; float* as2 = as1 + 2 * N; float* ad2 = as1 + 3 * N;
  float*          self1 = (float*)alloc((size_t)2 * N * 4); float* self2 = self1 + N;
  unsigned*       m1e   = (unsigned*)alloc((size_t)2 * N * 4); unsigned* m2e = m1e + N;
  float*          m1    = (float*)alloc((size_t)2 * N * 4); float* m2 = m1 + N;
  float*          den1  = (float*)alloc((size_t)2 * N * 4); float* den2 = den1 + N;
  int*            counts= (int*)alloc((size_t)N * 4);
  int*            offs  = (int*)alloc((size_t)(N + 1) * 4);
  int*            cursor= (int*)alloc((size_t)N * 4);
  int*            pose  = (int*)alloc((size_t)E * 4);
  int*            nsrc  = (int*)alloc((size_t)E * 4);
  float*          nw1   = (float*)alloc((size_t)E * 4);
  float*          nw2   = (float*)alloc((size_t)E * 4);
  float*          colsum= (float*)alloc(OUT_C * 4);
  float*          wv    = (float*)alloc(OUT_C * 4);
  float*          att   = (float*)alloc(OUT_C * 4);
  float* hout1 = (float*)d_out;

  dim3 tb(32, 8);
  cvt_x_kernel<<<(N * IN_C / 4 + 255) / 256, 256, 0, stream>>>(x, xb, N * IN_C / 4);
  transpose_cvt_kernel<<<dim3(OUT_C / 32, IN_C / 32), tb, 0, stream>>>(W1, WT, IN_C, OUT_C, 0);
  transpose_cvt_kernel<<<dim3(OUT_C / 32, IN_C / 32), tb, 0, stream>>>(W2, WT, IN_C, OUT_C, OUT_C);
  transpose_cvt_kernel<<<dim3(OUT_C / 32, OUT_C / 32), tb, 0, stream>>>(Wp1, Wp1T, OUT_C, OUT_C, 0);
  uv_kernel<<<512, 256, 0, stream>>>(W1, W2, a_src1, a_dst1, a_src2, a_dst2, uv);
  alpha_kernel<<<N, 256, 0, stream>>>(x, uv, as1, ad1, as2, ad2, self1, self2, m1e, m2e);
  zero_kernel<<<(N + 255) / 256, 256, 0, stream>>>(counts, cursor, colsum, wv, N);
  hist_kernel<<<(E + 255) / 256, 256, 0, stream>>>(dstArr, counts, E);
  scan_kernel<<<1, 256, 0, stream>>>(counts, offs, N);
  scatter_kernel<<<(E + 255) / 256, 256, 0, stream>>>(dstArr, offs, cursor, pose, E);
  edgemax_kernel<<<(E + 255) / 256, 256, 0, stream>>>(srcArr, dstArr, as1, ad1, as2, ad2, m1e, m2e, E);
  denominit_kernel<<<(N + 255) / 256, 256, 0, stream>>>(m1e, m2e, self1, self2, m1, m2, den1, den2, N);
  edgeexp_kernel<<<(E + 255) / 256, 256, 0, stream>>>(srcArr, dstArr, as1, ad1, as2, ad2, m1, m2,
                                                      pose, nsrc, nw1, nw2, den1, den2, E);
  aggx_kernel<<<dim3(4, (N + 15) / 16), 256, 0, stream>>>(counts, offs, nsrc, nw1, nw2, den1, den2,
                                                          self1, self2, m1, m2, xb, xa1b, xa2b, N);
  gemmh_kernel<<<dim3(OUT_C / 128, (N + 127) / 128), 256, 0, stream>>>(
      xa1b, WT, b1, prelu_a, hout1, nullptr, nullptr, N, 0);
  gemmh_kernel<<<dim3(OUT_C / 128, (N + 127) / 128), 256, 0, stream>>>(
      xa2b, WT + (size_t)OUT_C * IN_C, b2, prelu_a, hout2, hout1, hsum, N, 1);
  gemm2_kernel<<<dim3(OUT_C / 128, (N + 127) / 128), 256, 0, stream>>>(hsum, Wp1T, bp1, colsum, N);
  wproj_kernel<<<dim3(4, 8), 256, 0, stream>>>(colsum, Wp2, wv);
  softmax_kernel<<<1, 1024, 0, stream>>>(wv, att, 1.0f / (float)N);
  combine_kernel<<<(N * OUT_C / 4 + 255) / 256, 256, 0, stream>>>(att, hout1, hout2, (float*)d_out, N * OUT_C / 4);
}

// Round 5
// 366.637 us; speedup vs baseline: 1.1029x; 1.1029x over previous
//
#include <hip/hip_runtime.h>

#define IN_C 512
#define OUT_C 1024
#define NC2 2048
#define NEG_SLOPE 0.2f

typedef short frag8 __attribute__((ext_vector_type(8)));
typedef float f32x4 __attribute__((ext_vector_type(4)));

#define GLOAD_LDS16(g, l) __builtin_amdgcn_global_load_lds(\
    (const __attribute__((address_space(1))) void*)(g), \
    (__attribute__((address_space(3))) void*)(l), 16, 0, 0)

__device__ __forceinline__ unsigned short f2b(float f){
  unsigned u = __float_as_uint(f);
  unsigned r = (u + 0x7fffu + ((u >> 16) & 1u)) >> 16;
  return (unsigned short)r;
}
__device__ __forceinline__ unsigned encf(float f){
  unsigned u = __float_as_uint(f);
  return (u & 0x80000000u) ? ~u : (u | 0x80000000u);
}
__device__ __forceinline__ float decf(unsigned u){
  unsigned v = (u & 0x80000000u) ? (u & 0x7fffffffu) : ~u;
  return __uint_as_float(v);
}
__device__ __forceinline__ float leaky(float v){ return v >= 0.f ? v : NEG_SLOPE * v; }

// ---------------- conversion / transpose ----------------

__global__ void cvt_x_kernel(const float* __restrict__ x, unsigned short* __restrict__ xb, int total4){
  int i = blockIdx.x * 256 + threadIdx.x;
  if (i >= total4) return;
  float4 v = ((const float4*)x)[i];
  ushort4 o;
  o.x = f2b(v.x); o.y = f2b(v.y); o.z = f2b(v.z); o.w = f2b(v.w);
  ((ushort4*)xb)[i] = o;
}

// z selects W1/W2; out[(c + z*OUT_C)][r] = bf16(in_z[r][c]), out row stride R=IN_C
__global__ void transposeW_kernel(const float* __restrict__ W1, const float* __restrict__ W2,
                                  unsigned short* __restrict__ out){
  __shared__ float tile[32][33];
  const float* in = blockIdx.z ? W2 : W1;
  int rowOff = blockIdx.z * OUT_C;
  int c0 = blockIdx.x * 32, r0 = blockIdx.y * 32;
  for (int i = threadIdx.y; i < 32; i += 8)
    tile[i][threadIdx.x] = in[(size_t)(r0 + i) * OUT_C + c0 + threadIdx.x];
  __syncthreads();
  for (int i = threadIdx.y; i < 32; i += 8)
    out[(size_t)(c0 + i + rowOff) * IN_C + r0 + threadIdx.x] = f2b(tile[threadIdx.x][i]);
}

__global__ void transpose_cvt_kernel(const float* __restrict__ in, unsigned short* __restrict__ out,
                                     int R, int C){
  __shared__ float tile[32][33];
  int c0 = blockIdx.x * 32, r0 = blockIdx.y * 32;
  for (int i = threadIdx.y; i < 32; i += 8)
    tile[i][threadIdx.x] = in[(size_t)(r0 + i) * C + c0 + threadIdx.x];
  __syncthreads();
  for (int i = threadIdx.y; i < 32; i += 8)
    out[(size_t)(c0 + i) * R + r0 + threadIdx.x] = f2b(tile[threadIdx.x][i]);
}

// ---------------- attention-logit precompute ----------------

__global__ void uv_kernel(const float* __restrict__ W1, const float* __restrict__ W2,
                          const float* __restrict__ a_src1, const float* __restrict__ a_dst1,
                          const float* __restrict__ a_src2, const float* __restrict__ a_dst2,
                          float* __restrict__ uv){
  int g = blockIdx.x * 4 + (threadIdx.x >> 6);
  int lane = threadIdx.x & 63;
  int which = g >> 9;
  int i = g & 511;
  const float* W = (which < 2) ? W1 : W2;
  const float* a = (which == 0) ? a_src1 : (which == 1) ? a_dst1 : (which == 2) ? a_src2 : a_dst2;
  const float* row = W + (size_t)i * OUT_C;
  float s = 0.f;
  for (int j = lane; j < OUT_C; j += 64) s += row[j] * a[j];
  for (int off = 32; off; off >>= 1) s += __shfl_down(s, off);
  if (lane == 0) uv[which * IN_C + i] = s;
}

// alpha + fused selfinit
__global__ void alpha_kernel(const float* __restrict__ x, const float* __restrict__ uv,
                             float* __restrict__ as1, float* __restrict__ ad1,
                             float* __restrict__ as2, float* __restrict__ ad2,
                             float* __restrict__ self1, float* __restrict__ self2,
                             unsigned* __restrict__ m1e, unsigned* __restrict__ m2e){
  int n = blockIdx.x;
  int w = threadIdx.x >> 6, lane = threadIdx.x & 63;
  __shared__ float sh[4];
  const float* row = x + (size_t)n * IN_C;
  const float* u = uv + w * IN_C;
  float s = 0.f;
  for (int j = lane; j < IN_C; j += 64) s += row[j] * u[j];
  for (int off = 32; off; off >>= 1) s += __shfl_down(s, off);
  if (lane == 0){
    sh[w] = s;
    if (w == 0) as1[n] = s;
    else if (w == 1) ad1[n] = s;
    else if (w == 2) as2[n] = s;
    else ad2[n] = s;
  }
  __syncthreads();
  if (threadIdx.x == 0){
    float e1 = leaky(sh[0] + sh[1]);
    float e2 = leaky(sh[2] + sh[3]);
    self1[n] = e1; self2[n] = e2;
    m1e[n] = encf(e1); m2e[n] = encf(e2);
  }
}

// ---------------- CSR build + edge softmax (fused passes) ----------------

__global__ void zero_kernel(int* counts, int* cursor, float* colsum, float* wv, int N){
  int i = blockIdx.x * 256 + threadIdx.x;
  if (i < N){ counts[i] = 0; cursor[i] = 0; }
  if (i < OUT_C){ colsum[i] = 0.f; wv[i] = 0.f; }
}

// histogram + per-dst max in one edge pass
__global__ void histmax_kernel(const int* __restrict__ src, const int* __restrict__ dst,
                               const float* __restrict__ as1, const float* __restrict__ ad1,
                               const float* __restrict__ as2, const float* __restrict__ ad2,
                               int* counts, unsigned* m1e, unsigned* m2e, int E){
  int e = blockIdx.x * 256 + threadIdx.x;
  if (e >= E) return;
  int s = src[e], d = dst[e];
  atomicAdd(&counts[d], 1);
  atomicMax(&m1e[d], encf(leaky(as1[s] + ad1[d])));
  atomicMax(&m2e[d], encf(leaky(as2[s] + ad2[d])));
}

__global__ void scan_kernel(const int* __restrict__ counts, int* __restrict__ offs, int n){
  __shared__ int wsum[4];
  int tid = threadIdx.x;
  int wave = tid >> 6, lane = tid & 63;
  int carry = 0;
  for (int base = 0; base < n; base += 256){
    int i = base + tid;
    int v = (i < n) ? counts[i] : 0;
    int sc = v;
    for (int o = 1; o < 64; o <<= 1){
      int t = __shfl_up(sc, o);
      if (lane >= o) sc += t;
    }
    if (lane == 63) wsum[wave] = sc;
    __syncthreads();
    int wp = 0, tot = 0;
#pragma unroll
    for (int k = 0; k < 4; k++){
      int ws = wsum[k];
      if (k < wave) wp += ws;
      tot += ws;
    }
    if (i < n) offs[i] = carry + wp + sc - v;
    carry += tot;
    __syncthreads();
  }
}

__global__ void denominit_kernel(const unsigned* __restrict__ m1e, const unsigned* __restrict__ m2e,
                                 const float* __restrict__ self1, const float* __restrict__ self2,
                                 float* __restrict__ m1, float* __restrict__ m2,
                                 float* __restrict__ den1, float* __restrict__ den2, int N){
  int i = blockIdx.x * 256 + threadIdx.x;
  if (i >= N) return;
  float a = decf(m1e[i]), b = decf(m2e[i]);
  m1[i] = a; m2[i] = b;
  den1[i] = expf(self1[i] - a);
  den2[i] = expf(self2[i] - b);
}

// scatter to CSR + exp + denom accumulate in one edge pass
__global__ void scatterexp_kernel(const int* __restrict__ src, const int* __restrict__ dst,
                                  const int* __restrict__ offs, int* cursor,
                                  const float* __restrict__ as1, const float* __restrict__ ad1,
                                  const float* __restrict__ as2, const float* __restrict__ ad2,
                                  const float* __restrict__ m1, const float* __restrict__ m2,
                                  int* __restrict__ nsrc, float* __restrict__ nw1, float* __restrict__ nw2,
                                  float* den1, float* den2, int E){
  int e = blockIdx.x * 256 + threadIdx.x;
  if (e >= E) return;
  int s = src[e], d = dst[e];
  int p = atomicAdd(&cursor[d], 1);
  int idx = offs[d] + p;
  float x1 = expf(leaky(as1[s] + ad1[d]) - m1[d]);
  float x2 = expf(leaky(as2[s] + ad2[d]) - m2[d]);
  nsrc[idx] = s; nw1[idx] = x1; nw2[idx] = x2;
  atomicAdd(&den1[d], x1);
  atomicAdd(&den2[d], x2);
}

// ---------------- aggregate-first: xa_w[d][:] = sum_e w_e * x[src_e][:] ----------------

#define AGG_FMA8(ACC, W, U) \
  ACC[0] += (W) * __uint_as_float(((unsigned)(U).x) << 16); \
  ACC[1] += (W) * __uint_as_float(((unsigned)(U).x) & 0xffff0000u); \
  ACC[2] += (W) * __uint_as_float(((unsigned)(U).y) << 16); \
  ACC[3] += (W) * __uint_as_float(((unsigned)(U).y) & 0xffff0000u); \
  ACC[4] += (W) * __uint_as_float(((unsigned)(U).z) << 16); \
  ACC[5] += (W) * __uint_as_float(((unsigned)(U).z) & 0xffff0000u); \
  ACC[6] += (W) * __uint_as_float(((unsigned)(U).w) << 16); \
  ACC[7] += (W) * __uint_as_float(((unsigned)(U).w) & 0xffff0000u);

__global__ __launch_bounds__(256) void aggx_kernel(
    const int* __restrict__ counts, const int* __restrict__ offs,
    const int* __restrict__ nsrc, const float* __restrict__ nw1, const float* __restrict__ nw2,
    const float* __restrict__ den1, const float* __restrict__ den2,
    const float* __restrict__ self1, const float* __restrict__ self2,
    const float* __restrict__ m1, const float* __restrict__ m2,
    const unsigned short* __restrict__ xb,
    unsigned short* __restrict__ xa1b, unsigned short* __restrict__ xa2b, int N){
  int tid = threadIdx.x;
  int g = tid >> 4, hl = tid & 15;
  int grpbase = tid & 48;
  int d = blockIdx.y * 16 + g;
  if (d >= N) return;
  int colbase = blockIdx.x * 128 + hl * 8;
  float inv1 = 1.f / den1[d], inv2 = 1.f / den2[d];
  int deg = counts[d], off = offs[d];
  float acc1[8] = {0,0,0,0,0,0,0,0}, acc2[8] = {0,0,0,0,0,0,0,0};
  const unsigned short* Xb = xb + colbase;
  for (int base = 0; base < deg; base += 16){
    int i = base + hl;
    int s = 0; float w1 = 0.f, w2 = 0.f;
    if (i < deg){
      int p = off + i;
      s = nsrc[p];
      w1 = nw1[p] * inv1;
      w2 = nw2[p] * inv2;
    }
    int cnt = min(16, deg - base);
#pragma unroll 4
    for (int j = 0; j < cnt; j++){
      int sj = __shfl(s, grpbase + j);
      float w1j = __shfl(w1, grpbase + j);
      float w2j = __shfl(w2, grpbase + j);
      int4 u = *(const int4*)(Xb + (size_t)sj * IN_C);
      AGG_FMA8(acc1, w1j, u)
      AGG_FMA8(acc2, w2j, u)
    }
  }
  {
    float ws1 = expf(self1[d] - m1[d]) * inv1;
    float ws2 = expf(self2[d] - m2[d]) * inv2;
    int4 u = *(const int4*)(Xb + (size_t)d * IN_C);
    AGG_FMA8(acc1, ws1, u)
    AGG_FMA8(acc2, ws2, u)
  }
  size_t outb = (size_t)d * IN_C + colbase;
  int4 o1, o2;
  o1.x = (int)((unsigned)f2b(acc1[0]) | ((unsigned)f2b(acc1[1]) << 16));
  o1.y = (int)((unsigned)f2b(acc1[2]) | ((unsigned)f2b(acc1[3]) << 16));
  o1.z = (int)((unsigned)f2b(acc1[4]) | ((unsigned)f2b(acc1[5]) << 16));
  o1.w = (int)((unsigned)f2b(acc1[6]) | ((unsigned)f2b(acc1[7]) << 16));
  o2.x = (int)((unsigned)f2b(acc2[0]) | ((unsigned)f2b(acc2[1]) << 16));
  o2.y = (int)((unsigned)f2b(acc2[2]) | ((unsigned)f2b(acc2[3]) << 16));
  o2.z = (int)((unsigned)f2b(acc2[4]) | ((unsigned)f2b(acc2[5]) << 16));
  o2.w = (int)((unsigned)f2b(acc2[6]) | ((unsigned)f2b(acc2[7]) << 16));
  *(int4*)(xa1b + outb) = o1;
  *(int4*)(xa2b + outb) = o2;
}

// ---------------- fused GEMM-H: h1=prelu(xa1@W1+b1), h2=prelu(xa2@W2+b2), hsum=bf16(h1+h2) ---
// Both GEMMs in one kernel (sequential K-loops, shared LDS); all outputs bf16.

__global__ __launch_bounds__(256) void gemmh_kernel(const unsigned short* __restrict__ A1,
                                                    const unsigned short* __restrict__ A2,
                                                    const unsigned short* __restrict__ BT,
                                                    const float* __restrict__ b1,
                                                    const float* __restrict__ b2,
                                                    const float* __restrict__ prelu_a,
                                                    unsigned short* __restrict__ h1b,
                                                    unsigned short* __restrict__ h2b,
                                                    unsigned short* __restrict__ hsum, int M){
  __shared__ unsigned short Al[128 * 32];
  __shared__ unsigned short Bl[128 * 32];
  const int t = threadIdx.x;
  const int lane = t & 63, wid = t >> 6;
  const int wi = wid & 1, wj = wid >> 1;
  const int l16 = lane & 15, q = lane >> 4;
  const int bm = blockIdx.y * 128, bn = blockIdx.x * 128;
  const int lrow = lane >> 2;
  const int lch = (lane & 3) * 8;
  f32x4 acc1[4][4] = {};
  f32x4 acc2[4][4] = {};
  const int r0 = wid * 32 + lrow;
  const int r1 = r0 + 16;
  const int ga0 = min(bm + r0, M - 1);
  const int ga1 = min(bm + r1, M - 1);
  // ---- GEMM 1: xa1 @ W1 ----
  for (int k0 = 0; k0 < IN_C; k0 += 32){
    GLOAD_LDS16(A1 + (size_t)ga0 * IN_C + k0 + lch, &Al[(wid * 32) * 32]);
    GLOAD_LDS16(A1 + (size_t)ga1 * IN_C + k0 + lch, &Al[(wid * 32 + 16) * 32]);
    GLOAD_LDS16(BT + (size_t)(bn + r0) * IN_C + k0 + lch, &Bl[(wid * 32) * 32]);
    GLOAD_LDS16(BT + (size_t)(bn + r1) * IN_C + k0 + lch, &Bl[(wid * 32 + 16) * 32]);
    __syncthreads();
    frag8 af[4], bf[4];
#pragma unroll
    for (int mi = 0; mi < 4; mi++) af[mi] = *(const frag8*)&Al[(wi*64 + mi*16 + l16) * 32 + q*8];
#pragma unroll
    for (int nj = 0; nj < 4; nj++) bf[nj] = *(const frag8*)&Bl[(wj*64 + nj*16 + l16) * 32 + q*8];
#pragma unroll
    for (int mi = 0; mi < 4; mi++)
#pragma unroll
      for (int nj = 0; nj < 4; nj++)
        acc1[mi][nj] = __builtin_amdgcn_mfma_f32_16x16x32_bf16(af[mi], bf[nj], acc1[mi][nj], 0, 0, 0);
    __syncthreads();
  }
  // ---- GEMM 2: xa2 @ W2 (W2^T rows at offset OUT_C) ----
  for (int k0 = 0; k0 < IN_C; k0 += 32){
    GLOAD_LDS16(A2 + (size_t)ga0 * IN_C + k0 + lch, &Al[(wid * 32) * 32]);
    GLOAD_LDS16(A2 + (size_t)ga1 * IN_C + k0 + lch, &Al[(wid * 32 + 16) * 32]);
    GLOAD_LDS16(BT + (size_t)(OUT_C + bn + r0) * IN_C + k0 + lch, &Bl[(wid * 32) * 32]);
    GLOAD_LDS16(BT + (size_t)(OUT_C + bn + r1) * IN_C + k0 + lch, &Bl[(wid * 32 + 16) * 32]);
    __syncthreads();
    frag8 af[4], bf[4];
#pragma unroll
    for (int mi = 0; mi < 4; mi++) af[mi] = *(const frag8*)&Al[(wi*64 + mi*16 + l16) * 32 + q*8];
#pragma unroll
    for (int nj = 0; nj < 4; nj++) bf[nj] = *(const frag8*)&Bl[(wj*64 + nj*16 + l16) * 32 + q*8];
#pragma unroll
    for (int mi = 0; mi < 4; mi++)
#pragma unroll
      for (int nj = 0; nj < 4; nj++)
        acc2[mi][nj] = __builtin_amdgcn_mfma_f32_16x16x32_bf16(af[mi], bf[nj], acc2[mi][nj], 0, 0, 0);
    __syncthreads();
  }
  float pa = prelu_a[0];
#pragma unroll
  for (int mi = 0; mi < 4; mi++){
#pragma unroll
    for (int r = 0; r < 4; r++){
      int row = bm + wi*64 + mi*16 + q*4 + r;
      if (row >= M) continue;
#pragma unroll
      for (int nj = 0; nj < 4; nj++){
        int col = bn + wj*64 + nj*16 + l16;
        float v1 = acc1[mi][nj][r] + b1[col];
        v1 = v1 >= 0.f ? v1 : pa * v1;
        float v2 = acc2[mi][nj][r] + b2[col];
        v2 = v2 >= 0.f ? v2 : pa * v2;
        size_t idx = (size_t)row * OUT_C + col;
        h1b[idx] = f2b(v1);
        h2b[idx] = f2b(v2);
        hsum[idx] = f2b(v1 + v2);
      }
    }
  }
}

// ---------------- GEMM2: colsum += sum_rows tanh(hsum @ Wp1 + bp1) ----------------

__global__ __launch_bounds__(256) void gemm2_kernel(const unsigned short* __restrict__ A,
                                                    const unsigned short* __restrict__ BT,
                                                    const float* __restrict__ bp1,
                                                    float* __restrict__ colsum, int M){
  __shared__ unsigned short Al[128 * 32];
  __shared__ unsigned short Bl[128 * 32];
  __shared__ float cs[128];
  const int t = threadIdx.x;
  const int lane = t & 63, wid = t >> 6;
  const int wi = wid & 1, wj = wid >> 1;
  const int l16 = lane & 15, q = lane >> 4;
  const int bm = blockIdx.y * 128, bn = blockIdx.x * 128;
  const int lrow = lane >> 2;
  const int lch = (lane & 3) * 8;
  if (t < 128) cs[t] = 0.f;
  f32x4 acc[4][4] = {};
  for (int k0 = 0; k0 < OUT_C; k0 += 32){
    int r0 = wid * 32 + lrow;
    int r1 = r0 + 16;
    int ga0 = min(bm + r0, M - 1);
    int ga1 = min(bm + r1, M - 1);
    GLOAD_LDS16(A + (size_t)ga0 * OUT_C + k0 + lch, &Al[(wid * 32) * 32]);
    GLOAD_LDS16(A + (size_t)ga1 * OUT_C + k0 + lch, &Al[(wid * 32 + 16) * 32]);
    GLOAD_LDS16(BT + (size_t)(bn + r0) * OUT_C + k0 + lch, &Bl[(wid * 32) * 32]);
    GLOAD_LDS16(BT + (size_t)(bn + r1) * OUT_C + k0 + lch, &Bl[(wid * 32 + 16) * 32]);
    __syncthreads();
    frag8 af[4], bf[4];
#pragma unroll
    for (int mi = 0; mi < 4; mi++) af[mi] = *(const frag8*)&Al[(wi*64 + mi*16 + l16) * 32 + q*8];
#pragma unroll
    for (int nj = 0; nj < 4; nj++) bf[nj] = *(const frag8*)&Bl[(wj*64 + nj*16 + l16) * 32 + q*8];
#pragma unroll
    for (int mi = 0; mi < 4; mi++)
#pragma unroll
      for (int nj = 0; nj < 4; nj++)
        acc[mi][nj] = __builtin_amdgcn_mfma_f32_16x16x32_bf16(af[mi], bf[nj], acc[mi][nj], 0, 0, 0);
    __syncthreads();
  }
#pragma unroll
  for (int nj = 0; nj < 4; nj++){
    int col = bn + wj*64 + nj*16 + l16;
    float bias = bp1[col];
    float p = 0.f;
#pragma unroll
    for (int mi = 0; mi < 4; mi++){
#pragma unroll
      for (int r = 0; r < 4; r++){
        int row = bm + wi*64 + mi*16 + q*4 + r;
        float tv = tanhf(acc[mi][nj][r] + bias);
        if (row < M) p += tv;
      }
    }
    p += __shfl_xor(p, 16);
    p += __shfl_xor(p, 32);
    if (q == 0) atomicAdd(&cs[wj*64 + nj*16 + l16], p);
  }
  __syncthreads();
  if (t < 128) atomicAdd(&colsum[bn + t], cs[t]);
}

// ---------------- semantic attention tail ----------------

__global__ void wproj_kernel(const float* __restrict__ colsum, const float* __restrict__ Wp2,
                             float* __restrict__ wv){
  int o = blockIdx.x * 256 + threadIdx.x;
  int c0 = blockIdx.y * 128;
  float acc = 0.f;
  for (int c = c0; c < c0 + 128; c++) acc += colsum[c] * Wp2[(size_t)c * OUT_C + o];
  atomicAdd(&wv[o], acc);
}

__global__ __launch_bounds__(1024) void softmax_kernel(const float* __restrict__ wv,
                                                       float* __restrict__ att, float invN){
  int o = threadIdx.x;
  __shared__ float red[1024];
  float w = wv[o] * invN;
  red[o] = w; __syncthreads();
  for (int s = 512; s > 0; s >>= 1){ if (o < s) red[o] = fmaxf(red[o], red[o + s]); __syncthreads(); }
  float m = red[0]; __syncthreads();
  float e = expf(w - m);
  red[o] = e; __syncthreads();
  for (int s = 512; s > 0; s >>= 1){ if (o < s) red[o] += red[o + s]; __syncthreads(); }
  att[o] = e / red[0];
}

// out = att*h1 + (1-att)*h2, h1/h2 bf16, 8 cols per thread
__global__ void combine_kernel(const float* __restrict__ att, const unsigned short* __restrict__ h1,
                               const unsigned short* __restrict__ h2, float* __restrict__ out, int total8){
  int i = blockIdx.x * 256 + threadIdx.x;
  if (i >= total8) return;
  int colb = (i & 127) * 8;
  int4 u1 = ((const int4*)h1)[i];
  int4 u2 = ((const int4*)h2)[i];
  float4 a0 = *(const float4*)(att + colb);
  float4 a1 = *(const float4*)(att + colb + 4);
  float o[8];
  float v1, v2;
  v1 = __uint_as_float(((unsigned)u1.x) << 16);       v2 = __uint_as_float(((unsigned)u2.x) << 16);
  o[0] = a0.x * v1 + (1.f - a0.x) * v2;
  v1 = __uint_as_float(((unsigned)u1.x) & 0xffff0000u); v2 = __uint_as_float(((unsigned)u2.x) & 0xffff0000u);
  o[1] = a0.y * v1 + (1.f - a0.y) * v2;
  v1 = __uint_as_float(((unsigned)u1.y) << 16);       v2 = __uint_as_float(((unsigned)u2.y) << 16);
  o[2] = a0.z * v1 + (1.f - a0.z) * v2;
  v1 = __uint_as_float(((unsigned)u1.y) & 0xffff0000u); v2 = __uint_as_float(((unsigned)u2.y) & 0xffff0000u);
  o[3] = a0.w * v1 + (1.f - a0.w) * v2;
  v1 = __uint_as_float(((unsigned)u1.z) << 16);       v2 = __uint_as_float(((unsigned)u2.z) << 16);
  o[4] = a1.x * v1 + (1.f - a1.x) * v2;
  v1 = __uint_as_float(((unsigned)u1.z) & 0xffff0000u); v2 = __uint_as_float(((unsigned)u2.z) & 0xffff0000u);
  o[5] = a1.y * v1 + (1.f - a1.y) * v2;
  v1 = __uint_as_float(((unsigned)u1.w) << 16);       v2 = __uint_as_float(((unsigned)u2.w) << 16);
  o[6] = a1.z * v1 + (1.f - a1.z) * v2;
  v1 = __uint_as_float(((unsigned)u1.w) & 0xffff0000u); v2 = __uint_as_float(((unsigned)u2.w) & 0xffff0000u);
  o[7] = a1.w * v1 + (1.f - a1.w) * v2;
  float4 f0; f0.x = o[0]; f0.y = o[1]; f0.z = o[2]; f0.w = o[3];
  float4 f1; f1.x = o[4]; f1.y = o[5]; f1.z = o[6]; f1.w = o[7];
  *(float4*)(out + (size_t)i * 8) = f0;
  *(float4*)(out + (size_t)i * 8 + 4) = f1;
}

// ---------------- launch ----------------

extern "C" void kernel_launch(void* const* d_in, const int* in_sizes, int n_in,
                              void* d_out, int out_size, void* d_ws, size_t ws_size,
                              hipStream_t stream){
  const float* x      = (const float*)d_in[0];
  const int*   edge   = (const int*)d_in[1];
  const float* W1     = (const float*)d_in[2];
  const float* a_src1 = (const float*)d_in[3];
  const float* a_dst1 = (const float*)d_in[4];
  const float* b1     = (const float*)d_in[5];
  const float* W2     = (const float*)d_in[6];
  const float* a_src2 = (const float*)d_in[7];
  const float* a_dst2 = (const float*)d_in[8];
  const float* b2     = (const float*)d_in[9];
  const float* prelu_a= (const float*)d_in[10];
  const float* Wp1    = (const float*)d_in[11];
  const float* bp1    = (const float*)d_in[12];
  const float* Wp2    = (const float*)d_in[13];
  const int N = in_sizes[0] / IN_C;
  const int E = in_sizes[1] / 2;
  const int* srcArr = edge;
  const int* dstArr = edge + E;

  char* ws = (char*)d_ws;
  size_t o = 0;
  auto alloc = [&](size_t b) -> char* {
    char* p = ws + o;
    o = (o + b + 255) & ~(size_t)255;
    return p;
  };
  unsigned short* xb    = (unsigned short*)alloc((size_t)N * IN_C * 2);
  unsigned short* WT    = (unsigned short*)alloc((size_t)NC2 * IN_C * 2);   // [2048][512]: W1^T | W2^T
  unsigned short* Wp1T  = (unsigned short*)alloc((size_t)OUT_C * OUT_C * 2);
  unsigned short* xa1b  = (unsigned short*)alloc((size_t)N * IN_C * 2);
  unsigned short* xa2b  = (unsigned short*)alloc((size_t)N * IN_C * 2);
  unsigned short* h1b   = (unsigned short*)alloc((size_t)N * OUT_C * 2);
  unsigned short* h2b   = (unsigned short*)alloc((size_t)N * OUT_C * 2);
  unsigned short* hsum  = (unsigned short*)alloc((size_t)N * OUT_C * 2);
  float*          uv    = (float*)alloc(4 * IN_C * 4);
  float*          as1   = (float*)alloc((size_t)4 * N * 4);
  float* ad1 = as1 + N; float* as2 = as1 + 2 * N; float* ad2 = as1 + 3 * N;
  float*          self1 = (float*)alloc((size_t)2 * N * 4); float* self2 = self1 + N;
  unsigned*       m1e   = (unsigned*)alloc((size_t)2 * N * 4); unsigned* m2e = m1e + N;
  float*          m1    = (float*)alloc((size_t)2 * N * 4); float* m2 = m1 + N;
  float*          den1  = (float*)alloc((size_t)2 * N * 4); float* den2 = den1 + N;
  int*            counts= (int*)alloc((size_t)N * 4);
  int*            offs  = (int*)alloc((size_t)(N + 1) * 4);
  int*            cursor= (int*)alloc((size_t)N * 4);
  int*            nsrc  = (int*)alloc((size_t)E * 4);
  float*          nw1   = (float*)alloc((size_t)E * 4);
  float*          nw2   = (float*)alloc((size_t)E * 4);
  float*          colsum= (float*)alloc(OUT_C * 4);
  float*          wv    = (float*)alloc(OUT_C * 4);
  float*          att   = (float*)alloc(OUT_C * 4);

  dim3 tb(32, 8);
  cvt_x_kernel<<<(N * IN_C / 4 + 255) / 256, 256, 0, stream>>>(x, xb, N * IN_C / 4);
  transposeW_kernel<<<dim3(OUT_C / 32, IN_C / 32, 2), tb, 0, stream>>>(W1, W2, WT);
  transpose_cvt_kernel<<<dim3(OUT_C / 32, OUT_C / 32), tb, 0, stream>>>(Wp1, Wp1T, OUT_C, OUT_C);
  uv_kernel<<<512, 256, 0, stream>>>(W1, W2, a_src1, a_dst1, a_src2, a_dst2, uv);
  alpha_kernel<<<N, 256, 0, stream>>>(x, uv, as1, ad1, as2, ad2, self1, self2, m1e, m2e);
  zero_kernel<<<(N + 255) / 256, 256, 0, stream>>>(counts, cursor, colsum, wv, N);
  histmax_kernel<<<(E + 255) / 256, 256, 0, stream>>>(srcArr, dstArr, as1, ad1, as2, ad2,
                                                      counts, m1e, m2e, E);
  scan_kernel<<<1, 256, 0, stream>>>(counts, offs, N);
  denominit_kernel<<<(N + 255) / 256, 256, 0, stream>>>(m1e, m2e, self1, self2, m1, m2, den1, den2, N);
  scatterexp_kernel<<<(E + 255) / 256, 256, 0, stream>>>(srcArr, dstArr, offs, cursor,
                                                         as1, ad1, as2, ad2, m1, m2,
                                                         nsrc, nw1, nw2, den1, den2, E);
  aggx_kernel<<<dim3(4, (N + 15) / 16), 256, 0, stream>>>(counts, offs, nsrc, nw1, nw2, den1, den2,
                                                          self1, self2, m1, m2, xb, xa1b, xa2b, N);
  gemmh_kernel<<<dim3(OUT_C / 128, (N + 127) / 128), 256, 0, stream>>>(
      xa1b, xa2b, WT, b1, b2, prelu_a, h1b, h2b, hsum, N);
  gemm2_kernel<<<dim3(OUT_C / 128, (N + 127) / 128), 256, 0, stream>>>(hsum, Wp1T, bp1, colsum, N);
  wproj_kernel<<<dim3(4, 8), 256, 0, stream>>>(colsum, Wp2, wv);
  softmax_kernel<<<1, 1024, 0, stream>>>(wv, att, 1.0f / (float)N);
  combine_kernel<<<(N * OUT_C / 8 + 255) / 256, 256, 0, stream>>>(att, h1b, h2b, (float*)d_out,
                                                                  N * OUT_C / 8);
}

// Round 6
// 358.506 us; speedup vs baseline: 1.1279x; 1.0227x over previous
//
#include <hip/hip_runtime.h>

#define IN_C 512
#define OUT_C 1024
#define NC2 2048
#define NEG_SLOPE 0.2f

typedef short frag8 __attribute__((ext_vector_type(8)));
typedef float f32x4 __attribute__((ext_vector_type(4)));

#define GLOAD_LDS16(g, l) __builtin_amdgcn_global_load_lds(\
    (const __attribute__((address_space(1))) void*)(g), \
    (__attribute__((address_space(3))) void*)(l), 16, 0, 0)

__device__ __forceinline__ unsigned short f2b(float f){
  unsigned u = __float_as_uint(f);
  unsigned r = (u + 0x7fffu + ((u >> 16) & 1u)) >> 16;
  return (unsigned short)r;
}
__device__ __forceinline__ unsigned encf(float f){
  unsigned u = __float_as_uint(f);
  return (u & 0x80000000u) ? ~u : (u | 0x80000000u);
}
__device__ __forceinline__ float decf(unsigned u){
  unsigned v = (u & 0x80000000u) ? (u & 0x7fffffffu) : ~u;
  return __uint_as_float(v);
}
__device__ __forceinline__ float leaky(float v){ return v >= 0.f ? v : NEG_SLOPE * v; }

// ---------------- transpose ----------------

// z selects W1/W2; out[(c + z*OUT_C)][r] = bf16(in_z[r][c]), out row stride R=IN_C
__global__ void transposeW_kernel(const float* __restrict__ W1, const float* __restrict__ W2,
                                  unsigned short* __restrict__ out){
  __shared__ float tile[32][33];
  const float* in = blockIdx.z ? W2 : W1;
  int rowOff = blockIdx.z * OUT_C;
  int c0 = blockIdx.x * 32, r0 = blockIdx.y * 32;
  for (int i = threadIdx.y; i < 32; i += 8)
    tile[i][threadIdx.x] = in[(size_t)(r0 + i) * OUT_C + c0 + threadIdx.x];
  __syncthreads();
  for (int i = threadIdx.y; i < 32; i += 8)
    out[(size_t)(c0 + i + rowOff) * IN_C + r0 + threadIdx.x] = f2b(tile[threadIdx.x][i]);
}

__global__ void transpose_cvt_kernel(const float* __restrict__ in, unsigned short* __restrict__ out,
                                     int R, int C){
  __shared__ float tile[32][33];
  int c0 = blockIdx.x * 32, r0 = blockIdx.y * 32;
  for (int i = threadIdx.y; i < 32; i += 8)
    tile[i][threadIdx.x] = in[(size_t)(r0 + i) * C + c0 + threadIdx.x];
  __syncthreads();
  for (int i = threadIdx.y; i < 32; i += 8)
    out[(size_t)(c0 + i) * R + r0 + threadIdx.x] = f2b(tile[threadIdx.x][i]);
}

// ---------------- attention-logit precompute ----------------

__global__ void uv_kernel(const float* __restrict__ W1, const float* __restrict__ W2,
                          const float* __restrict__ a_src1, const float* __restrict__ a_dst1,
                          const float* __restrict__ a_src2, const float* __restrict__ a_dst2,
                          float* __restrict__ uv){
  int g = blockIdx.x * 4 + (threadIdx.x >> 6);
  int lane = threadIdx.x & 63;
  int which = g >> 9;
  int i = g & 511;
  const float* W = (which < 2) ? W1 : W2;
  const float* a = (which == 0) ? a_src1 : (which == 1) ? a_dst1 : (which == 2) ? a_src2 : a_dst2;
  const float* row = W + (size_t)i * OUT_C;
  float s = 0.f;
  for (int j = lane; j < OUT_C; j += 64) s += row[j] * a[j];
  for (int off = 32; off; off >>= 1) s += __shfl_down(s, off);
  if (lane == 0) uv[which * IN_C + i] = s;
}

// alpha + selfinit + x->bf16 conversion (wave 0 writes xb)
__global__ void alpha_kernel(const float* __restrict__ x, const float* __restrict__ uv,
                             unsigned short* __restrict__ xb,
                             float* __restrict__ as1, float* __restrict__ ad1,
                             float* __restrict__ as2, float* __restrict__ ad2,
                             float* __restrict__ self1, float* __restrict__ self2,
                             unsigned* __restrict__ m1e, unsigned* __restrict__ m2e){
  int n = blockIdx.x;
  int w = threadIdx.x >> 6, lane = threadIdx.x & 63;
  __shared__ float sh[4];
  const float* row = x + (size_t)n * IN_C;
  const float* u = uv + w * IN_C;
  float s = 0.f;
  for (int j = lane; j < IN_C; j += 64){
    float v = row[j];
    s += v * u[j];
    if (w == 0) xb[(size_t)n * IN_C + j] = f2b(v);
  }
  for (int off = 32; off; off >>= 1) s += __shfl_down(s, off);
  if (lane == 0){
    sh[w] = s;
    if (w == 0) as1[n] = s;
    else if (w == 1) ad1[n] = s;
    else if (w == 2) as2[n] = s;
    else ad2[n] = s;
  }
  __syncthreads();
  if (threadIdx.x == 0){
    float e1 = leaky(sh[0] + sh[1]);
    float e2 = leaky(sh[2] + sh[3]);
    self1[n] = e1; self2[n] = e2;
    m1e[n] = encf(e1); m2e[n] = encf(e2);
  }
}

// ---------------- CSR build + edge softmax (fused passes) ----------------

__global__ void zero_kernel(int* counts, int* cursor, float* colsum, float* wv, int N){
  int i = blockIdx.x * 256 + threadIdx.x;
  if (i < N){ counts[i] = 0; cursor[i] = 0; }
  if (i < OUT_C){ colsum[i] = 0.f; wv[i] = 0.f; }
}

__global__ void histmax_kernel(const int* __restrict__ src, const int* __restrict__ dst,
                               const float* __restrict__ as1, const float* __restrict__ ad1,
                               const float* __restrict__ as2, const float* __restrict__ ad2,
                               int* counts, unsigned* m1e, unsigned* m2e, int E){
  int e = blockIdx.x * 256 + threadIdx.x;
  if (e >= E) return;
  int s = src[e], d = dst[e];
  atomicAdd(&counts[d], 1);
  atomicMax(&m1e[d], encf(leaky(as1[s] + ad1[d])));
  atomicMax(&m2e[d], encf(leaky(as2[s] + ad2[d])));
}

__global__ void scan_kernel(const int* __restrict__ counts, int* __restrict__ offs, int n){
  __shared__ int wsum[4];
  int tid = threadIdx.x;
  int wave = tid >> 6, lane = tid & 63;
  int carry = 0;
  for (int base = 0; base < n; base += 256){
    int i = base + tid;
    int v = (i < n) ? counts[i] : 0;
    int sc = v;
    for (int o = 1; o < 64; o <<= 1){
      int t = __shfl_up(sc, o);
      if (lane >= o) sc += t;
    }
    if (lane == 63) wsum[wave] = sc;
    __syncthreads();
    int wp = 0, tot = 0;
#pragma unroll
    for (int k = 0; k < 4; k++){
      int ws = wsum[k];
      if (k < wave) wp += ws;
      tot += ws;
    }
    if (i < n) offs[i] = carry + wp + sc - v;
    carry += tot;
    __syncthreads();
  }
}

__global__ void denominit_kernel(const unsigned* __restrict__ m1e, const unsigned* __restrict__ m2e,
                                 const float* __restrict__ self1, const float* __restrict__ self2,
                                 float* __restrict__ m1, float* __restrict__ m2,
                                 float* __restrict__ den1, float* __restrict__ den2, int N){
  int i = blockIdx.x * 256 + threadIdx.x;
  if (i >= N) return;
  float a = decf(m1e[i]), b = decf(m2e[i]);
  m1[i] = a; m2[i] = b;
  den1[i] = expf(self1[i] - a);
  den2[i] = expf(self2[i] - b);
}

__global__ void scatterexp_kernel(const int* __restrict__ src, const int* __restrict__ dst,
                                  const int* __restrict__ offs, int* cursor,
                                  const float* __restrict__ as1, const float* __restrict__ ad1,
                                  const float* __restrict__ as2, const float* __restrict__ ad2,
                                  const float* __restrict__ m1, const float* __restrict__ m2,
                                  int* __restrict__ nsrc, float* __restrict__ nw1, float* __restrict__ nw2,
                                  float* den1, float* den2, int E){
  int e = blockIdx.x * 256 + threadIdx.x;
  if (e >= E) return;
  int s = src[e], d = dst[e];
  int p = atomicAdd(&cursor[d], 1);
  int idx = offs[d] + p;
  float x1 = expf(leaky(as1[s] + ad1[d]) - m1[d]);
  float x2 = expf(leaky(as2[s] + ad2[d]) - m2[d]);
  nsrc[idx] = s; nw1[idx] = x1; nw2[idx] = x2;
  atomicAdd(&den1[d], x1);
  atomicAdd(&den2[d], x2);
}

// ---------------- aggregate-first: xa_w[d][:] = sum_e w_e * x[src_e][:] ----------------

#define AGG_FMA8(ACC, W, U) \
  ACC[0] += (W) * __uint_as_float(((unsigned)(U).x) << 16); \
  ACC[1] += (W) * __uint_as_float(((unsigned)(U).x) & 0xffff0000u); \
  ACC[2] += (W) * __uint_as_float(((unsigned)(U).y) << 16); \
  ACC[3] += (W) * __uint_as_float(((unsigned)(U).y) & 0xffff0000u); \
  ACC[4] += (W) * __uint_as_float(((unsigned)(U).z) << 16); \
  ACC[5] += (W) * __uint_as_float(((unsigned)(U).z) & 0xffff0000u); \
  ACC[6] += (W) * __uint_as_float(((unsigned)(U).w) << 16); \
  ACC[7] += (W) * __uint_as_float(((unsigned)(U).w) & 0xffff0000u);

__global__ __launch_bounds__(256) void aggx_kernel(
    const int* __restrict__ counts, const int* __restrict__ offs,
    const int* __restrict__ nsrc, const float* __restrict__ nw1, const float* __restrict__ nw2,
    const float* __restrict__ den1, const float* __restrict__ den2,
    const float* __restrict__ self1, const float* __restrict__ self2,
    const float* __restrict__ m1, const float* __restrict__ m2,
    const unsigned short* __restrict__ xb,
    unsigned short* __restrict__ xa1b, unsigned short* __restrict__ xa2b, int N){
  int tid = threadIdx.x;
  int g = tid >> 4, hl = tid & 15;
  int grpbase = tid & 48;
  int d = blockIdx.y * 16 + g;
  if (d >= N) return;
  int colbase = blockIdx.x * 128 + hl * 8;
  float inv1 = 1.f / den1[d], inv2 = 1.f / den2[d];
  int deg = counts[d], off = offs[d];
  float acc1[8] = {0,0,0,0,0,0,0,0}, acc2[8] = {0,0,0,0,0,0,0,0};
  const unsigned short* Xb = xb + colbase;
  for (int base = 0; base < deg; base += 16){
    int i = base + hl;
    int s = 0; float w1 = 0.f, w2 = 0.f;
    if (i < deg){
      int p = off + i;
      s = nsrc[p];
      w1 = nw1[p] * inv1;
      w2 = nw2[p] * inv2;
    }
    int cnt = min(16, deg - base);
#pragma unroll 4
    for (int j = 0; j < cnt; j++){
      int sj = __shfl(s, grpbase + j);
      float w1j = __shfl(w1, grpbase + j);
      float w2j = __shfl(w2, grpbase + j);
      int4 u = *(const int4*)(Xb + (size_t)sj * IN_C);
      AGG_FMA8(acc1, w1j, u)
      AGG_FMA8(acc2, w2j, u)
    }
  }
  {
    float ws1 = expf(self1[d] - m1[d]) * inv1;
    float ws2 = expf(self2[d] - m2[d]) * inv2;
    int4 u = *(const int4*)(Xb + (size_t)d * IN_C);
    AGG_FMA8(acc1, ws1, u)
    AGG_FMA8(acc2, ws2, u)
  }
  size_t outb = (size_t)d * IN_C + colbase;
  int4 o1, o2;
  o1.x = (int)((unsigned)f2b(acc1[0]) | ((unsigned)f2b(acc1[1]) << 16));
  o1.y = (int)((unsigned)f2b(acc1[2]) | ((unsigned)f2b(acc1[3]) << 16));
  o1.z = (int)((unsigned)f2b(acc1[4]) | ((unsigned)f2b(acc1[5]) << 16));
  o1.w = (int)((unsigned)f2b(acc1[6]) | ((unsigned)f2b(acc1[7]) << 16));
  o2.x = (int)((unsigned)f2b(acc2[0]) | ((unsigned)f2b(acc2[1]) << 16));
  o2.y = (int)((unsigned)f2b(acc2[2]) | ((unsigned)f2b(acc2[3]) << 16));
  o2.z = (int)((unsigned)f2b(acc2[4]) | ((unsigned)f2b(acc2[5]) << 16));
  o2.w = (int)((unsigned)f2b(acc2[6]) | ((unsigned)f2b(acc2[7]) << 16));
  *(int4*)(xa1b + outb) = o1;
  *(int4*)(xa2b + outb) = o2;
}

// ---------------- fused GEMM-H ----------------
// h1=prelu(xa1@W1+b1), h2=prelu(xa2@W2+b2); stores s=bf16(h1+h2), d=bf16(h1-h2).
// 1-D swizzled grid: xcd = bid%8 owns a contiguous band of M-tiles across all 8 N-tiles
// (A-band ~2.5 MB + B 2 MB fits the 4 MB per-XCD L2; bn cycles fastest for B reuse).

__global__ __launch_bounds__(256) void gemmh_kernel(const unsigned short* __restrict__ A1,
                                                    const unsigned short* __restrict__ A2,
                                                    const unsigned short* __restrict__ BT,
                                                    const float* __restrict__ b1,
                                                    const float* __restrict__ b2,
                                                    const float* __restrict__ prelu_a,
                                                    unsigned short* __restrict__ hsum,
                                                    unsigned short* __restrict__ hdiff,
                                                    int M, int Mtiles, int perx){
  const int bid = blockIdx.x;
  const int xcd = bid & 7;
  const int li = bid >> 3;
  const int bn_t = li & 7;
  const int bm_t = xcd * perx + (li >> 3);
  if (bm_t >= Mtiles) return;
  const int bm = bm_t * 128, bn = bn_t * 128;
  __shared__ unsigned short Al[128 * 32];
  __shared__ unsigned short Bl[128 * 32];
  const int t = threadIdx.x;
  const int lane = t & 63, wid = t >> 6;
  const int wi = wid & 1, wj = wid >> 1;
  const int l16 = lane & 15, q = lane >> 4;
  const int lrow = lane >> 2;
  const int lch = (lane & 3) * 8;
  f32x4 acc1[4][4] = {};
  f32x4 acc2[4][4] = {};
  const int r0 = wid * 32 + lrow;
  const int r1 = r0 + 16;
  const int ga0 = min(bm + r0, M - 1);
  const int ga1 = min(bm + r1, M - 1);
  for (int k0 = 0; k0 < IN_C; k0 += 32){
    GLOAD_LDS16(A1 + (size_t)ga0 * IN_C + k0 + lch, &Al[(wid * 32) * 32]);
    GLOAD_LDS16(A1 + (size_t)ga1 * IN_C + k0 + lch, &Al[(wid * 32 + 16) * 32]);
    GLOAD_LDS16(BT + (size_t)(bn + r0) * IN_C + k0 + lch, &Bl[(wid * 32) * 32]);
    GLOAD_LDS16(BT + (size_t)(bn + r1) * IN_C + k0 + lch, &Bl[(wid * 32 + 16) * 32]);
    __syncthreads();
    frag8 af[4], bf[4];
#pragma unroll
    for (int mi = 0; mi < 4; mi++) af[mi] = *(const frag8*)&Al[(wi*64 + mi*16 + l16) * 32 + q*8];
#pragma unroll
    for (int nj = 0; nj < 4; nj++) bf[nj] = *(const frag8*)&Bl[(wj*64 + nj*16 + l16) * 32 + q*8];
#pragma unroll
    for (int mi = 0; mi < 4; mi++)
#pragma unroll
      for (int nj = 0; nj < 4; nj++)
        acc1[mi][nj] = __builtin_amdgcn_mfma_f32_16x16x32_bf16(af[mi], bf[nj], acc1[mi][nj], 0, 0, 0);
    __syncthreads();
  }
  for (int k0 = 0; k0 < IN_C; k0 += 32){
    GLOAD_LDS16(A2 + (size_t)ga0 * IN_C + k0 + lch, &Al[(wid * 32) * 32]);
    GLOAD_LDS16(A2 + (size_t)ga1 * IN_C + k0 + lch, &Al[(wid * 32 + 16) * 32]);
    GLOAD_LDS16(BT + (size_t)(OUT_C + bn + r0) * IN_C + k0 + lch, &Bl[(wid * 32) * 32]);
    GLOAD_LDS16(BT + (size_t)(OUT_C + bn + r1) * IN_C + k0 + lch, &Bl[(wid * 32 + 16) * 32]);
    __syncthreads();
    frag8 af[4], bf[4];
#pragma unroll
    for (int mi = 0; mi < 4; mi++) af[mi] = *(const frag8*)&Al[(wi*64 + mi*16 + l16) * 32 + q*8];
#pragma unroll
    for (int nj = 0; nj < 4; nj++) bf[nj] = *(const frag8*)&Bl[(wj*64 + nj*16 + l16) * 32 + q*8];
#pragma unroll
    for (int mi = 0; mi < 4; mi++)
#pragma unroll
      for (int nj = 0; nj < 4; nj++)
        acc2[mi][nj] = __builtin_amdgcn_mfma_f32_16x16x32_bf16(af[mi], bf[nj], acc2[mi][nj], 0, 0, 0);
    __syncthreads();
  }
  float pa = prelu_a[0];
#pragma unroll
  for (int mi = 0; mi < 4; mi++){
#pragma unroll
    for (int r = 0; r < 4; r++){
      int row = bm + wi*64 + mi*16 + q*4 + r;
      if (row >= M) continue;
#pragma unroll
      for (int nj = 0; nj < 4; nj++){
        int col = bn + wj*64 + nj*16 + l16;
        float v1 = acc1[mi][nj][r] + b1[col];
        v1 = v1 >= 0.f ? v1 : pa * v1;
        float v2 = acc2[mi][nj][r] + b2[col];
        v2 = v2 >= 0.f ? v2 : pa * v2;
        size_t idx = (size_t)row * OUT_C + col;
        hsum[idx]  = f2b(v1 + v2);
        hdiff[idx] = f2b(v1 - v2);
      }
    }
  }
}

// ---------------- GEMM2: colsum += sum_rows tanh(hsum @ Wp1 + bp1) ----------------

__global__ __launch_bounds__(256) void gemm2_kernel(const unsigned short* __restrict__ A,
                                                    const unsigned short* __restrict__ BT,
                                                    const float* __restrict__ bp1,
                                                    float* __restrict__ colsum,
                                                    int M, int Mtiles, int perx){
  const int bid = blockIdx.x;
  const int xcd = bid & 7;
  const int li = bid >> 3;
  const int bn_t = li & 7;
  const int bm_t = xcd * perx + (li >> 3);
  if (bm_t >= Mtiles) return;
  const int bm = bm_t * 128, bn = bn_t * 128;
  __shared__ unsigned short Al[128 * 32];
  __shared__ unsigned short Bl[128 * 32];
  __shared__ float cs[128];
  const int t = threadIdx.x;
  const int lane = t & 63, wid = t >> 6;
  const int wi = wid & 1, wj = wid >> 1;
  const int l16 = lane & 15, q = lane >> 4;
  const int lrow = lane >> 2;
  const int lch = (lane & 3) * 8;
  if (t < 128) cs[t] = 0.f;
  f32x4 acc[4][4] = {};
  for (int k0 = 0; k0 < OUT_C; k0 += 32){
    int r0 = wid * 32 + lrow;
    int r1 = r0 + 16;
    int ga0 = min(bm + r0, M - 1);
    int ga1 = min(bm + r1, M - 1);
    GLOAD_LDS16(A + (size_t)ga0 * OUT_C + k0 + lch, &Al[(wid * 32) * 32]);
    GLOAD_LDS16(A + (size_t)ga1 * OUT_C + k0 + lch, &Al[(wid * 32 + 16) * 32]);
    GLOAD_LDS16(BT + (size_t)(bn + r0) * OUT_C + k0 + lch, &Bl[(wid * 32) * 32]);
    GLOAD_LDS16(BT + (size_t)(bn + r1) * OUT_C + k0 + lch, &Bl[(wid * 32 + 16) * 32]);
    __syncthreads();
    frag8 af[4], bf[4];
#pragma unroll
    for (int mi = 0; mi < 4; mi++) af[mi] = *(const frag8*)&Al[(wi*64 + mi*16 + l16) * 32 + q*8];
#pragma unroll
    for (int nj = 0; nj < 4; nj++) bf[nj] = *(const frag8*)&Bl[(wj*64 + nj*16 + l16) * 32 + q*8];
#pragma unroll
    for (int mi = 0; mi < 4; mi++)
#pragma unroll
      for (int nj = 0; nj < 4; nj++)
        acc[mi][nj] = __builtin_amdgcn_mfma_f32_16x16x32_bf16(af[mi], bf[nj], acc[mi][nj], 0, 0, 0);
    __syncthreads();
  }
#pragma unroll
  for (int nj = 0; nj < 4; nj++){
    int col = bn + wj*64 + nj*16 + l16;
    float bias = bp1[col];
    float p = 0.f;
#pragma unroll
    for (int mi = 0; mi < 4; mi++){
#pragma unroll
      for (int r = 0; r < 4; r++){
        int row = bm + wi*64 + mi*16 + q*4 + r;
        float tv = tanhf(acc[mi][nj][r] + bias);
        if (row < M) p += tv;
      }
    }
    p += __shfl_xor(p, 16);
    p += __shfl_xor(p, 32);
    if (q == 0) atomicAdd(&cs[wj*64 + nj*16 + l16], p);
  }
  __syncthreads();
  if (t < 128) atomicAdd(&colsum[bn + t], cs[t]);
}

// ---------------- semantic attention tail ----------------

__global__ void wproj_kernel(const float* __restrict__ colsum, const float* __restrict__ Wp2,
                             float* __restrict__ wv){
  int o = blockIdx.x * 256 + threadIdx.x;
  int c0 = blockIdx.y * 128;
  float acc = 0.f;
  for (int c = c0; c < c0 + 128; c++) acc += colsum[c] * Wp2[(size_t)c * OUT_C + o];
  atomicAdd(&wv[o], acc);
}

__global__ __launch_bounds__(1024) void softmax_kernel(const float* __restrict__ wv,
                                                       float* __restrict__ att, float invN){
  int o = threadIdx.x;
  __shared__ float red[1024];
  float w = wv[o] * invN;
  red[o] = w; __syncthreads();
  for (int s = 512; s > 0; s >>= 1){ if (o < s) red[o] = fmaxf(red[o], red[o + s]); __syncthreads(); }
  float m = red[0]; __syncthreads();
  float e = expf(w - m);
  red[o] = e; __syncthreads();
  for (int s = 512; s > 0; s >>= 1){ if (o < s) red[o] += red[o + s]; __syncthreads(); }
  att[o] = e / red[0];
}

// out = 0.5*s + (att-0.5)*d where s=h1+h2, d=h1-h2 (bf16); 8 cols per thread
__global__ void combine_kernel(const float* __restrict__ att, const unsigned short* __restrict__ hs,
                               const unsigned short* __restrict__ hd, float* __restrict__ out, int total8){
  int i = blockIdx.x * 256 + threadIdx.x;
  if (i >= total8) return;
  int colb = (i & 127) * 8;
  int4 us = ((const int4*)hs)[i];
  int4 ud = ((const int4*)hd)[i];
  float4 a0 = *(const float4*)(att + colb);
  float4 a1 = *(const float4*)(att + colb + 4);
  float o[8]; float sv, dv;
  sv = __uint_as_float(((unsigned)us.x) << 16);        dv = __uint_as_float(((unsigned)ud.x) << 16);
  o[0] = 0.5f * sv + (a0.x - 0.5f) * dv;
  sv = __uint_as_float(((unsigned)us.x) & 0xffff0000u); dv = __uint_as_float(((unsigned)ud.x) & 0xffff0000u);
  o[1] = 0.5f * sv + (a0.y - 0.5f) * dv;
  sv = __uint_as_float(((unsigned)us.y) << 16);        dv = __uint_as_float(((unsigned)ud.y) << 16);
  o[2] = 0.5f * sv + (a0.z - 0.5f) * dv;
  sv = __uint_as_float(((unsigned)us.y) & 0xffff0000u); dv = __uint_as_float(((unsigned)ud.y) & 0xffff0000u);
  o[3] = 0.5f * sv + (a0.w - 0.5f) * dv;
  sv = __uint_as_float(((unsigned)us.z) << 16);        dv = __uint_as_float(((unsigned)ud.z) << 16);
  o[4] = 0.5f * sv + (a1.x - 0.5f) * dv;
  sv = __uint_as_float(((unsigned)us.z) & 0xffff0000u); dv = __uint_as_float(((unsigned)ud.z) & 0xffff0000u);
  o[5] = 0.5f * sv + (a1.y - 0.5f) * dv;
  sv = __uint_as_float(((unsigned)us.w) << 16);        dv = __uint_as_float(((unsigned)ud.w) << 16);
  o[6] = 0.5f * sv + (a1.z - 0.5f) * dv;
  sv = __uint_as_float(((unsigned)us.w) & 0xffff0000u); dv = __uint_as_float(((unsigned)ud.w) & 0xffff0000u);
  o[7] = 0.5f * sv + (a1.w - 0.5f) * dv;
  float4 f0; f0.x = o[0]; f0.y = o[1]; f0.z = o[2]; f0.w = o[3];
  float4 f1; f1.x = o[4]; f1.y = o[5]; f1.z = o[6]; f1.w = o[7];
  *(float4*)(out + (size_t)i * 8) = f0;
  *(float4*)(out + (size_t)i * 8 + 4) = f1;
}

// ---------------- launch ----------------

extern "C" void kernel_launch(void* const* d_in, const int* in_sizes, int n_in,
                              void* d_out, int out_size, void* d_ws, size_t ws_size,
                              hipStream_t stream){
  const float* x      = (const float*)d_in[0];
  const int*   edge   = (const int*)d_in[1];
  const float* W1     = (const float*)d_in[2];
  const float* a_src1 = (const float*)d_in[3];
  const float* a_dst1 = (const float*)d_in[4];
  const float* b1     = (const float*)d_in[5];
  const float* W2     = (const float*)d_in[6];
  const float* a_src2 = (const float*)d_in[7];
  const float* a_dst2 = (const float*)d_in[8];
  const float* b2     = (const float*)d_in[9];
  const float* prelu_a= (const float*)d_in[10];
  const float* Wp1    = (const float*)d_in[11];
  const float* bp1    = (const float*)d_in[12];
  const float* Wp2    = (const float*)d_in[13];
  const int N = in_sizes[0] / IN_C;
  const int E = in_sizes[1] / 2;
  const int* srcArr = edge;
  const int* dstArr = edge + E;

  char* ws = (char*)d_ws;
  size_t o = 0;
  auto alloc = [&](size_t b) -> char* {
    char* p = ws + o;
    o = (o + b + 255) & ~(size_t)255;
    return p;
  };
  unsigned short* xb    = (unsigned short*)alloc((size_t)N * IN_C * 2);
  unsigned short* WT    = (unsigned short*)alloc((size_t)NC2 * IN_C * 2);   // [2048][512]: W1^T | W2^T
  unsigned short* Wp1T  = (unsigned short*)alloc((size_t)OUT_C * OUT_C * 2);
  unsigned short* xa1b  = (unsigned short*)alloc((size_t)N * IN_C * 2);
  unsigned short* xa2b  = (unsigned short*)alloc((size_t)N * IN_C * 2);
  unsigned short* hsum  = (unsigned short*)alloc((size_t)N * OUT_C * 2);
  unsigned short* hdiff = (unsigned short*)alloc((size_t)N * OUT_C * 2);
  float*          uv    = (float*)alloc(4 * IN_C * 4);
  float*          as1   = (float*)alloc((size_t)4 * N * 4);
  float* ad1 = as1 + N; float* as2 = as1 + 2 * N; float* ad2 = as1 + 3 * N;
  float*          self1 = (float*)alloc((size_t)2 * N * 4); float* self2 = self1 + N;
  unsigned*       m1e   = (unsigned*)alloc((size_t)2 * N * 4); unsigned* m2e = m1e + N;
  float*          m1    = (float*)alloc((size_t)2 * N * 4); float* m2 = m1 + N;
  float*          den1  = (float*)alloc((size_t)2 * N * 4); float* den2 = den1 + N;
  int*            counts= (int*)alloc((size_t)N * 4);
  int*            offs  = (int*)alloc((size_t)(N + 1) * 4);
  int*            cursor= (int*)alloc((size_t)N * 4);
  int*            nsrc  = (int*)alloc((size_t)E * 4);
  float*          nw1   = (float*)alloc((size_t)E * 4);
  float*          nw2   = (float*)alloc((size_t)E * 4);
  float*          colsum= (float*)alloc(OUT_C * 4);
  float*          wv    = (float*)alloc(OUT_C * 4);
  float*          att   = (float*)alloc(OUT_C * 4);

  const int Mtiles = (N + 127) / 128;
  const int perx = (Mtiles + 7) / 8;
  const int gemmgrid = 8 * perx * 8;

  dim3 tb(32, 8);
  transposeW_kernel<<<dim3(OUT_C / 32, IN_C / 32, 2), tb, 0, stream>>>(W1, W2, WT);
  transpose_cvt_kernel<<<dim3(OUT_C / 32, OUT_C / 32), tb, 0, stream>>>(Wp1, Wp1T, OUT_C, OUT_C);
  uv_kernel<<<512, 256, 0, stream>>>(W1, W2, a_src1, a_dst1, a_src2, a_dst2, uv);
  alpha_kernel<<<N, 256, 0, stream>>>(x, uv, xb, as1, ad1, as2, ad2, self1, self2, m1e, m2e);
  zero_kernel<<<(N + 255) / 256, 256, 0, stream>>>(counts, cursor, colsum, wv, N);
  histmax_kernel<<<(E + 255) / 256, 256, 0, stream>>>(srcArr, dstArr, as1, ad1, as2, ad2,
                                                      counts, m1e, m2e, E);
  scan_kernel<<<1, 256, 0, stream>>>(counts, offs, N);
  denominit_kernel<<<(N + 255) / 256, 256, 0, stream>>>(m1e, m2e, self1, self2, m1, m2, den1, den2, N);
  scatterexp_kernel<<<(E + 255) / 256, 256, 0, stream>>>(srcArr, dstArr, offs, cursor,
                                                         as1, ad1, as2, ad2, m1, m2,
                                                         nsrc, nw1, nw2, den1, den2, E);
  aggx_kernel<<<dim3(4, (N + 15) / 16), 256, 0, stream>>>(counts, offs, nsrc, nw1, nw2, den1, den2,
                                                          self1, self2, m1, m2, xb, xa1b, xa2b, N);
  gemmh_kernel<<<gemmgrid, 256, 0, stream>>>(xa1b, xa2b, WT, b1, b2, prelu_a,
                                             hsum, hdiff, N, Mtiles, perx);
  gemm2_kernel<<<gemmgrid, 256, 0, stream>>>(hsum, Wp1T, bp1, colsum, N, Mtiles, perx);
  wproj_kernel<<<dim3(4, 8), 256, 0, stream>>>(colsum, Wp2, wv);
  softmax_kernel<<<1, 1024, 0, stream>>>(wv, att, 1.0f / (float)N);
  combine_kernel<<<(N * OUT_C / 8 + 255) / 256, 256, 0, stream>>>(att, hsum, hdiff, (float*)d_out,
                                                                  N * OUT_C / 8);
}